// Round 3
// baseline (278.706 us; speedup 1.0000x reference)
//
#include <hip/hip_runtime.h>

#define D 1024
#define EPS 1e-5f

typedef float v4f __attribute__((ext_vector_type(4)));

// One WAVE per token: 256-thread block = 4 waves = 4 tokens.
// Each lane handles 16 elements (4 x int4 loads). LayerNorm stats via
// 64-lane shuffle butterfly -- no cross-wave reduction, single barrier
// (only for the LDS code-table staging).
__global__ __launch_bounds__(256) void emb_deq_ln_kernel(
    const int*   __restrict__ x,       // [T] token ids (int32 from harness)
    const int*   __restrict__ w,       // [V, D] int codes 0..255
    const float* __restrict__ absmax,  // [V*D/4096]; row v uses absmax[v>>2]
    const float* __restrict__ code,    // [256]
    const float* __restrict__ ln_w,    // [D]
    const float* __restrict__ ln_b,    // [D]
    float*       __restrict__ out,     // [T, D]
    int T)
{
    __shared__ float code_s[256];

    const int tid  = threadIdx.x;
    const int lane = tid & 63;
    const int wid  = tid >> 6;

    // Stage code table (exactly 256 threads).
    code_s[tid] = code[tid];

    int t = blockIdx.x * 4 + wid;
    t = min(t, T - 1);  // tail clamp (duplicates rewrite same row; benign)

    const int   v     = x[t];
    const float scale = absmax[v >> 2];

    // Issue all 4 coalesced 16B row loads before the barrier (MLP).
    const int4* __restrict__ wrow = (const int4*)(w + (size_t)v * D);
    const int4 q0 = wrow[lane];
    const int4 q1 = wrow[lane + 64];
    const int4 q2 = wrow[lane + 128];
    const int4 q3 = wrow[lane + 192];

    // LN params (read-only, L2-resident after first blocks).
    const float4* lw4 = (const float4*)ln_w;
    const float4* lb4 = (const float4*)ln_b;
    const float4 lw0 = lw4[lane];       const float4 lb0 = lb4[lane];
    const float4 lw1 = lw4[lane + 64];  const float4 lb1 = lb4[lane + 64];
    const float4 lw2 = lw4[lane + 128]; const float4 lb2 = lb4[lane + 128];
    const float4 lw3 = lw4[lane + 192]; const float4 lb3 = lb4[lane + 192];

    __syncthreads();  // code_s ready

    float4 v0, v1, v2, v3;
    v0.x = code_s[q0.x] * scale; v0.y = code_s[q0.y] * scale;
    v0.z = code_s[q0.z] * scale; v0.w = code_s[q0.w] * scale;
    v1.x = code_s[q1.x] * scale; v1.y = code_s[q1.y] * scale;
    v1.z = code_s[q1.z] * scale; v1.w = code_s[q1.w] * scale;
    v2.x = code_s[q2.x] * scale; v2.y = code_s[q2.y] * scale;
    v2.z = code_s[q2.z] * scale; v2.w = code_s[q2.w] * scale;
    v3.x = code_s[q3.x] * scale; v3.y = code_s[q3.y] * scale;
    v3.z = code_s[q3.z] * scale; v3.w = code_s[q3.w] * scale;

    float s  = (v0.x + v0.y + v0.z + v0.w) + (v1.x + v1.y + v1.z + v1.w)
             + (v2.x + v2.y + v2.z + v2.w) + (v3.x + v3.y + v3.z + v3.w);
    float ss = (v0.x*v0.x + v0.y*v0.y + v0.z*v0.z + v0.w*v0.w)
             + (v1.x*v1.x + v1.y*v1.y + v1.z*v1.z + v1.w*v1.w)
             + (v2.x*v2.x + v2.y*v2.y + v2.z*v2.z + v2.w*v2.w)
             + (v3.x*v3.x + v3.y*v3.y + v3.z*v3.z + v3.w*v3.w);

    // 64-lane butterfly: every lane ends with the full sums.
    #pragma unroll
    for (int off = 32; off > 0; off >>= 1) {
        s  += __shfl_xor(s,  off, 64);
        ss += __shfl_xor(ss, off, 64);
    }

    const float mean = s * (1.0f / D);
    const float rstd = rsqrtf(ss * (1.0f / D) - mean * mean + EPS);

    v4f* orow = (v4f*)(out + (size_t)t * D);
    v4f o;
    o.x = (v0.x - mean) * rstd * lw0.x + lb0.x;
    o.y = (v0.y - mean) * rstd * lw0.y + lb0.y;
    o.z = (v0.z - mean) * rstd * lw0.z + lb0.z;
    o.w = (v0.w - mean) * rstd * lw0.w + lb0.w;
    __builtin_nontemporal_store(o, &orow[lane]);
    o.x = (v1.x - mean) * rstd * lw1.x + lb1.x;
    o.y = (v1.y - mean) * rstd * lw1.y + lb1.y;
    o.z = (v1.z - mean) * rstd * lw1.z + lb1.z;
    o.w = (v1.w - mean) * rstd * lw1.w + lb1.w;
    __builtin_nontemporal_store(o, &orow[lane + 64]);
    o.x = (v2.x - mean) * rstd * lw2.x + lb2.x;
    o.y = (v2.y - mean) * rstd * lw2.y + lb2.y;
    o.z = (v2.z - mean) * rstd * lw2.z + lb2.z;
    o.w = (v2.w - mean) * rstd * lw2.w + lb2.w;
    __builtin_nontemporal_store(o, &orow[lane + 128]);
    o.x = (v3.x - mean) * rstd * lw3.x + lb3.x;
    o.y = (v3.y - mean) * rstd * lw3.y + lb3.y;
    o.z = (v3.z - mean) * rstd * lw3.z + lb3.z;
    o.w = (v3.w - mean) * rstd * lw3.w + lb3.w;
    __builtin_nontemporal_store(o, &orow[lane + 192]);
}

extern "C" void kernel_launch(void* const* d_in, const int* in_sizes, int n_in,
                              void* d_out, int out_size, void* d_ws, size_t ws_size,
                              hipStream_t stream) {
    const int*   x      = (const int*)d_in[0];
    const int*   w      = (const int*)d_in[1];
    const float* absmax = (const float*)d_in[2];
    const float* code   = (const float*)d_in[3];
    const float* ln_w   = (const float*)d_in[4];
    const float* ln_b   = (const float*)d_in[5];
    float* out = (float*)d_out;

    const int T = in_sizes[0];  // 8 * 2048 = 16384 tokens

    const int grid = (T + 3) / 4;  // 4 tokens (waves) per block
    emb_deq_ln_kernel<<<grid, 256, 0, stream>>>(x, w, absmax, code, ln_w, ln_b, out, T);
}